// Round 6
// baseline (297.104 us; speedup 1.0000x reference)
//
#include <hip/hip_runtime.h>
#include <math.h>

typedef _Float16 f16;
typedef _Float16 f16x8 __attribute__((ext_vector_type(8)));
typedef float f32x4 __attribute__((ext_vector_type(4)));

// ---------------------------------------------------------------------------
// Kernel A (MFMA): per-point MLP layers 1-2.  Block = 512 points (4 m-tiles
// of 128).  h1 fragments built in-register, layer2 via f16 MFMA with W2
// B-fragments resident.  Epilogue: bias+relu+cvt, LDS transpose, plain
// full-row burst store (row-major [pt][128] f16).
// ---------------------------------------------------------------------------
__global__ __launch_bounds__(256, 2) void pointnet_l12(
    const float* __restrict__ x,
    const float* __restrict__ W1, const float* __restrict__ b1,
    const float* __restrict__ W2, const float* __restrict__ b2,
    f16* __restrict__ h2)
{
    __shared__ float xs[512*3];                    // 6 KB
    __shared__ float w1s[192], b1s[64], b2s[128];  // 1.5 KB
    __shared__ __align__(16) f16 h2s[128*136];     // 34.8 KB, +8 pad per row

    int tid = threadIdx.x;
    int P0 = blockIdx.x * 512;
    for (int i = tid; i < 1536; i += 256) xs[i] = x[(size_t)P0*3 + i];
    if (tid < 192) w1s[tid] = W1[tid];
    else b1s[tid - 192] = b1[tid - 192];
    if (tid < 128) b2s[tid] = b2[tid];

    int lane = tid & 63, wid = tid >> 6;
    int wr = wid & 1, wc = wid >> 1;
    int lrow = lane & 15, quad = lane >> 4;

    // B-fragments direct from fp32 W2 [64 k][128 n] (L2-resident, once/block)
    f16x8 bf[4][2];
#pragma unroll
    for (int ct = 0; ct < 4; ct++)
#pragma unroll
        for (int kc = 0; kc < 2; kc++) {
            int col = wc*64 + ct*16 + lrow;
#pragma unroll
            for (int j = 0; j < 8; j++)
                bf[ct][kc][j] = (f16)W2[(size_t)(kc*32 + quad*8 + j)*128 + col];
        }

    __syncthreads();

    for (int mt = 0; mt < 4; mt++) {
        f32x4 acc[4][4];
#pragma unroll
        for (int rt = 0; rt < 4; rt++)
#pragma unroll
            for (int ct = 0; ct < 4; ct++)
                acc[rt][ct] = (f32x4){0.f, 0.f, 0.f, 0.f};

#pragma unroll
        for (int kc = 0; kc < 2; kc++) {
            float wa[8], wb[8], wcv[8], bv[8];
#pragma unroll
            for (int j = 0; j < 8; j++) {
                int k = kc*32 + quad*8 + j;
                wa[j] = w1s[k]; wb[j] = w1s[64+k]; wcv[j] = w1s[128+k]; bv[j] = b1s[k];
            }
            f16x8 af[4];
#pragma unroll
            for (int rt = 0; rt < 4; rt++) {
                int p = mt*128 + wr*64 + rt*16 + lrow;
                float x0 = xs[p*3], x1 = xs[p*3+1], x2 = xs[p*3+2];
#pragma unroll
                for (int j = 0; j < 8; j++) {
                    float v = fmaf(x2, wcv[j], fmaf(x1, wb[j], fmaf(x0, wa[j], bv[j])));
                    af[rt][j] = (f16)fmaxf(v, 0.f);
                }
            }
#pragma unroll
            for (int rt = 0; rt < 4; rt++)
#pragma unroll
                for (int ct = 0; ct < 4; ct++)
                    acc[rt][ct] = __builtin_amdgcn_mfma_f32_16x16x32_f16(af[rt], bf[ct][kc], acc[rt][ct], 0, 0, 0);
        }

        __syncthreads();   // previous tile's h2s readers done
#pragma unroll
        for (int rt = 0; rt < 4; rt++)
#pragma unroll
            for (int ct = 0; ct < 4; ct++) {
                int col  = wc*64 + ct*16 + lrow;
                float bb = b2s[col];
                int rowb = wr*64 + rt*16 + quad*4;
#pragma unroll
                for (int r = 0; r < 4; r++) {
                    float v = fmaxf(acc[rt][ct][r] + bb, 0.f);
                    h2s[(rowb + r)*136 + col] = (f16)v;
                }
            }
        __syncthreads();
        // burst store: full rows, plain row-major
        size_t gbase = ((size_t)P0 + (size_t)mt*128) * 128;
#pragma unroll
        for (int i = 0; i < 8; i++) {
            int e = i*256 + tid;
            int row = e >> 4, c = e & 15;
            f16x8 v = *(const f16x8*)(h2s + row*136 + c*8);
            *(f16x8*)(h2 + gbase + (size_t)row*128 + c*8) = v;
        }
    }
}

// ---------------------------------------------------------------------------
// Kernel B: h2[1024x128] @ W3[128x1024] (f16 MFMA), bias+relu+max over points
// -> g[B][1024].  NO LDS, NO barriers: B-fragments (W3) resident in VGPRs,
// A-fragments loaded straight global->VGPR (64B-coalesced per row).  Block =
// (b, 256-col strip); decode b=i&255 => same-b blocks share i%8 => same XCD
// => the 4x A re-read is L2-served.  Waves self-paced; occupancy hides L2
// latency.
// ---------------------------------------------------------------------------
__global__ __launch_bounds__(256, 3) void pointnet_l3_max(
    const f16* __restrict__ h2,    // [B*1024][128] row-major
    const float* __restrict__ W3,  // [128][1024] fp32
    const float* __restrict__ b3,  // [1024]
    float* __restrict__ g)         // [B][1024]
{
    int i  = blockIdx.x;
    int b  = i & 255, nb = i >> 8;   // nb 0..3
    int tid = threadIdx.x;
    int lane = tid & 63, wid = tid >> 6;
    int lrow = lane & 15, quad = lane >> 4;
    int col0 = nb*256 + wid*64;

    // B-fragments direct from fp32 W3 [128 k][1024 n] (L2-resident)
    f16x8 bf[4][4];
#pragma unroll
    for (int ct = 0; ct < 4; ct++)
#pragma unroll
        for (int kc = 0; kc < 4; kc++) {
            int col = col0 + ct*16 + lrow;
#pragma unroll
            for (int j = 0; j < 8; j++)
                bf[ct][kc][j] = (f16)W3[(size_t)(kc*32 + quad*8 + j)*1024 + col];
        }

    float cmax[4] = {-3.0e38f, -3.0e38f, -3.0e38f, -3.0e38f};
    // per-lane A base: row component lrow, k component quad*8
    const f16* abase = h2 + (size_t)b * 1024 * 128 + (size_t)lrow * 128 + quad * 8;

    for (int m0 = 0; m0 < 1024; m0 += 128) {
#pragma unroll
        for (int half = 0; half < 2; half++) {
            f32x4 acc[4][4];
#pragma unroll
            for (int rt = 0; rt < 4; rt++)
#pragma unroll
                for (int ct = 0; ct < 4; ct++)
                    acc[rt][ct] = (f32x4){0.f, 0.f, 0.f, 0.f};
#pragma unroll
            for (int kc = 0; kc < 4; kc++) {
                f16x8 af[4];
#pragma unroll
                for (int rt = 0; rt < 4; rt++)
                    af[rt] = *(const f16x8*)(abase + (size_t)(m0 + half*64 + rt*16)*128 + kc*32);
#pragma unroll
                for (int rt = 0; rt < 4; rt++)
#pragma unroll
                    for (int ct = 0; ct < 4; ct++)
                        acc[rt][ct] = __builtin_amdgcn_mfma_f32_16x16x32_f16(af[rt], bf[ct][kc], acc[rt][ct], 0, 0, 0);
            }
            // fold rows into running col-max (bias+relu deferred: monotone)
#pragma unroll
            for (int rt = 0; rt < 4; rt++)
#pragma unroll
                for (int ct = 0; ct < 4; ct++)
#pragma unroll
                    for (int r = 0; r < 4; r += 2)
                        cmax[ct] = fmaxf(fmaxf(acc[rt][ct][r], acc[rt][ct][r+1]), cmax[ct]);
        }
    }

#pragma unroll
    for (int ct = 0; ct < 4; ct++) {
        cmax[ct] = fmaxf(cmax[ct], __shfl_xor(cmax[ct], 16, 64));
        cmax[ct] = fmaxf(cmax[ct], __shfl_xor(cmax[ct], 32, 64));
    }
    if (quad == 0) {
#pragma unroll
        for (int ct = 0; ct < 4; ct++) {
            int cg = col0 + ct*16 + lrow;
            g[(size_t)b*1024 + cg] = fmaxf(cmax[ct] + b3[cg], 0.f);
        }
    }
}

// ---------------------------------------------------------------------------
// Head layer 1 partials: zp1[kc][b][c] = sum_{k in chunk} g[b][k]*Wh1[k][c].
// Grid (cb=2, bb=64, kc=4) = 512 blocks; block 256 thr; 4 batches/block.
// ---------------------------------------------------------------------------
__global__ __launch_bounds__(256) void head_l1(
    const float* __restrict__ g, const float* __restrict__ Wh1,
    float* __restrict__ zp1)
{
    __shared__ float gs4[4][256];
    int cb = blockIdx.x, bb = blockIdx.y, kc = blockIdx.z;
    int tid = threadIdx.x;
    int b0 = bb * 4;
    int kbase = kc * 256;
#pragma unroll
    for (int j = 0; j < 4; j++) {
        int i = tid + j*256;
        gs4[i >> 8][i & 255] = g[(size_t)(b0 + (i >> 8))*1024 + kbase + (i & 255)];
    }
    __syncthreads();

    int c = cb*256 + tid;
    float acc[4] = {0.f, 0.f, 0.f, 0.f};
#pragma unroll 1
    for (int k = 0; k < 256; k += 8) {
        float w[8];
#pragma unroll
        for (int j = 0; j < 8; j++) w[j] = Wh1[(size_t)(kbase+k+j)*512 + c];
#pragma unroll
        for (int r = 0; r < 4; r++) {
            float4 a = *(const float4*)&gs4[r][k];
            float4 bq = *(const float4*)&gs4[r][k+4];
            acc[r] = fmaf(a.x, w[0], acc[r]);
            acc[r] = fmaf(a.y, w[1], acc[r]);
            acc[r] = fmaf(a.z, w[2], acc[r]);
            acc[r] = fmaf(a.w, w[3], acc[r]);
            acc[r] = fmaf(bq.x, w[4], acc[r]);
            acc[r] = fmaf(bq.y, w[5], acc[r]);
            acc[r] = fmaf(bq.z, w[6], acc[r]);
            acc[r] = fmaf(bq.w, w[7], acc[r]);
        }
    }
#pragma unroll
    for (int r = 0; r < 4; r++)
        zp1[((size_t)kc*256 + b0 + r)*512 + c] = acc[r];
}

// ---------------------------------------------------------------------------
// Head layer 2 partials, z1-reduce fused into staging.
// Grid (bb=128, kc2=4) = 512 blocks; block 256; 2 batches/block.
// ---------------------------------------------------------------------------
__global__ __launch_bounds__(256) void head_l2(
    const float* __restrict__ zp1, const float* __restrict__ bh1,
    const float* __restrict__ Wh2, float* __restrict__ zp2)
{
    __shared__ float z1s[2][128];
    int bb = blockIdx.x, kc2 = blockIdx.y;
    int tid = threadIdx.x;
    int b0 = bb * 2;
    int kb = kc2 * 128;
    {
        int row = tid >> 7, kk = tid & 127;
        int col = kb + kk;
        float v = bh1[col];
#pragma unroll
        for (int j = 0; j < 4; j++)
            v += zp1[((size_t)j*256 + b0 + row)*512 + col];
        z1s[row][kk] = fmaxf(v, 0.f);
    }
    __syncthreads();

    int c = tid;
    float acc0 = 0.f, acc1 = 0.f;
#pragma unroll 1
    for (int k = 0; k < 128; k += 8) {
        float w[8];
#pragma unroll
        for (int j = 0; j < 8; j++) w[j] = Wh2[(size_t)(kb+k+j)*256 + c];
        float4 a0 = *(const float4*)&z1s[0][k];
        float4 a1 = *(const float4*)&z1s[0][k+4];
        float4 d0 = *(const float4*)&z1s[1][k];
        float4 d1 = *(const float4*)&z1s[1][k+4];
        acc0 = fmaf(a0.x, w[0], acc0);  acc1 = fmaf(d0.x, w[0], acc1);
        acc0 = fmaf(a0.y, w[1], acc0);  acc1 = fmaf(d0.y, w[1], acc1);
        acc0 = fmaf(a0.z, w[2], acc0);  acc1 = fmaf(d0.z, w[2], acc1);
        acc0 = fmaf(a0.w, w[3], acc0);  acc1 = fmaf(d0.w, w[3], acc1);
        acc0 = fmaf(a1.x, w[4], acc0);  acc1 = fmaf(d1.x, w[4], acc1);
        acc0 = fmaf(a1.y, w[5], acc0);  acc1 = fmaf(d1.y, w[5], acc1);
        acc0 = fmaf(a1.z, w[6], acc0);  acc1 = fmaf(d1.z, w[6], acc1);
        acc0 = fmaf(a1.w, w[7], acc0);  acc1 = fmaf(d1.w, w[7], acc1);
    }
    zp2[((size_t)kc2*256 + b0    )*256 + c] = acc0;
    zp2[((size_t)kc2*256 + b0 + 1)*256 + c] = acc1;
}

// ---------------------------------------------------------------------------
// SVD -> SO(3) projection, fp64 Jacobi on M^T M (per-thread serial)
// ---------------------------------------------------------------------------
__device__ inline void jrot(double S[3][3], double V[3][3], int p, int q)
{
    double apq = S[p][q];
    if (fabs(apq) < 1e-36) return;
    double tau = (S[q][q] - S[p][p]) / (2.0 * apq);
    double t = (tau >= 0.0 ? 1.0 : -1.0) / (fabs(tau) + sqrt(1.0 + tau*tau));
    double c = 1.0 / sqrt(1.0 + t*t);
    double s = t * c;
    for (int k = 0; k < 3; k++) {
        double skp = S[k][p], skq = S[k][q];
        S[k][p] = c*skp - s*skq;  S[k][q] = s*skp + c*skq;
    }
    for (int k = 0; k < 3; k++) {
        double spk = S[p][k], sqk = S[q][k];
        S[p][k] = c*spk - s*sqk;  S[q][k] = s*spk + c*sqk;
    }
    for (int k = 0; k < 3; k++) {
        double vkp = V[k][p], vkq = V[k][q];
        V[k][p] = c*vkp - s*vkq;  V[k][q] = s*vkp + c*vkq;
    }
}

__device__ void svd_so3(const float* Mf, float* Rout)
{
    double M[3][3], S[3][3], V[3][3];
    for (int i = 0; i < 3; i++)
        for (int j = 0; j < 3; j++) M[i][j] = (double)Mf[3*i+j];
    for (int i = 0; i < 3; i++)
        for (int j = 0; j < 3; j++)
            S[i][j] = M[0][i]*M[0][j] + M[1][i]*M[1][j] + M[2][i]*M[2][j];
    for (int i = 0; i < 3; i++)
        for (int j = 0; j < 3; j++) V[i][j] = (i == j) ? 1.0 : 0.0;
    for (int it = 0; it < 10; it++) {
        jrot(S, V, 0, 1); jrot(S, V, 0, 2); jrot(S, V, 1, 2);
    }
    double lam[3] = {S[0][0], S[1][1], S[2][2]};
    int i0 = 0, i1 = 1, i2 = 2, tt;
    if (lam[i0] < lam[i1]) { tt = i0; i0 = i1; i1 = tt; }
    if (lam[i0] < lam[i2]) { tt = i0; i0 = i2; i2 = tt; }
    if (lam[i1] < lam[i2]) { tt = i1; i1 = i2; i2 = tt; }
    double v0[3], v1[3], v2[3];
    for (int k = 0; k < 3; k++) { v0[k] = V[k][i0]; v1[k] = V[k][i1]; v2[k] = V[k][i2]; }
    double u1[3], u2[3], u3[3];
    for (int i = 0; i < 3; i++) u1[i] = M[i][0]*v0[0] + M[i][1]*v0[1] + M[i][2]*v0[2];
    double n1 = sqrt(u1[0]*u1[0] + u1[1]*u1[1] + u1[2]*u1[2]) + 1e-300;
    for (int i = 0; i < 3; i++) u1[i] /= n1;
    for (int i = 0; i < 3; i++) u2[i] = M[i][0]*v1[0] + M[i][1]*v1[1] + M[i][2]*v1[2];
    double d12 = u1[0]*u2[0] + u1[1]*u2[1] + u1[2]*u2[2];
    for (int i = 0; i < 3; i++) u2[i] -= d12*u1[i];
    double n2 = sqrt(u2[0]*u2[0] + u2[1]*u2[1] + u2[2]*u2[2]) + 1e-300;
    for (int i = 0; i < 3; i++) u2[i] /= n2;
    u3[0] = u1[1]*u2[2] - u1[2]*u2[1];
    u3[1] = u1[2]*u2[0] - u1[0]*u2[2];
    u3[2] = u1[0]*u2[1] - u1[1]*u2[0];
    double c12x = v1[1]*v2[2] - v1[2]*v2[1];
    double c12y = v1[2]*v2[0] - v1[0]*v2[2];
    double c12z = v1[0]*v2[1] - v1[1]*v2[0];
    double detV = v0[0]*c12x + v0[1]*c12y + v0[2]*c12z;
    for (int i = 0; i < 3; i++)
        for (int j = 0; j < 3; j++)
            Rout[3*i+j] = (float)(u1[i]*v0[j] + u2[i]*v1[j] + detV*u3[i]*v2[j]);
}

// ---------------------------------------------------------------------------
// Head tail: z2-reduce + (z2 @ Wh3 + bh3) + SVD. Wh3 staged in LDS.
// 8 batches/block, 32 blocks x 128 threads.
// ---------------------------------------------------------------------------
__global__ __launch_bounds__(128) void head_l3_svd(
    const float* __restrict__ zp2, const float* __restrict__ bh2,
    const float* __restrict__ Wh3, const float* __restrict__ bh3,
    float* __restrict__ out)
{
    __shared__ float z2s[8][256];
    __shared__ float wh3s[2304];
    __shared__ float raws[8][12];
    int b0 = blockIdx.x * 8;
    int tid = threadIdx.x;

    for (int i = tid; i < 2304; i += 128) wh3s[i] = Wh3[i];
    for (int i = tid; i < 8*256; i += 128) {
        int row = i >> 8, kk = i & 255;
        float v = bh2[kk];
#pragma unroll
        for (int j = 0; j < 4; j++)
            v += zp2[((size_t)j*256 + b0 + row)*256 + kk];
        z2s[row][kk] = fmaxf(v, 0.f);
    }
    __syncthreads();

    if (tid < 72) {
        int r = tid / 9, c = tid % 9;
        float acc = bh3[c];
#pragma unroll 8
        for (int k = 0; k < 256; k++) acc = fmaf(z2s[r][k], wh3s[k*9 + c], acc);
        raws[r][c] = acc;
    }
    __syncthreads();

    if (tid < 8) svd_so3(&raws[tid][0], out + (size_t)(b0 + tid)*9);
}

// ---------------------------------------------------------------------------
extern "C" void kernel_launch(void* const* d_in, const int* in_sizes, int n_in,
                              void* d_out, int out_size, void* d_ws, size_t ws_size,
                              hipStream_t stream)
{
    const float* x   = (const float*)d_in[0];
    const float* W1  = (const float*)d_in[1];
    const float* b1  = (const float*)d_in[2];
    const float* W2  = (const float*)d_in[3];
    const float* b2  = (const float*)d_in[4];
    const float* W3  = (const float*)d_in[5];
    const float* b3  = (const float*)d_in[6];
    const float* Wh1 = (const float*)d_in[7];
    const float* bh1 = (const float*)d_in[8];
    const float* Wh2 = (const float*)d_in[9];
    const float* bh2 = (const float*)d_in[10];
    const float* Wh3 = (const float*)d_in[11];
    const float* bh3 = (const float*)d_in[12];
    float* out = (float*)d_out;

    char* ws = (char*)d_ws;
    f16*   h2  = (f16*)ws;                                  // 64 MB
    float* g   = (float*)(ws + (size_t)67108864);           // 1 MB
    float* zp1 = (float*)(ws + (size_t)67108864 + 1048576);            // 2 MB
    float* zp2 = (float*)(ws + (size_t)67108864 + 1048576 + 2097152);  // 1 MB

    pointnet_l12<<<512, 256, 0, stream>>>(x, W1, b1, W2, b2, h2);
    pointnet_l3_max<<<1024, 256, 0, stream>>>(h2, W3, b3, g);
    dim3 gridH1(2, 64, 4);
    head_l1<<<gridH1, 256, 0, stream>>>(g, Wh1, zp1);
    dim3 gridH2(128, 4);
    head_l2<<<gridH2, 256, 0, stream>>>(zp1, bh1, Wh2, zp2);
    head_l3_svd<<<32, 128, 0, stream>>>(zp2, bh2, Wh3, bh3, out);
}

// Round 7
// 192.976 us; speedup vs baseline: 1.5396x; 1.5396x over previous
//
#include <hip/hip_runtime.h>
#include <math.h>

typedef _Float16 f16;
typedef _Float16 f16x8 __attribute__((ext_vector_type(8)));
typedef float f32x4 __attribute__((ext_vector_type(4)));

// ---------------------------------------------------------------------------
// h2 is stored FRAGMENT-MAJOR: per batch, per 16-row group g (64 groups/batch),
// 256 chunks of 16B ordered [kc(4)][quad(4)][lrow(16)].  A wave's MFMA A-load
// for (group, kc) is then 64 consecutive chunks = 1 KB contiguous burst.
// chunk(g,kc,quad,lrow) = g*256 + kc*64 + quad*16 + lrow ; element = chunk*8.
// ---------------------------------------------------------------------------

// ---------------------------------------------------------------------------
// Kernel A (MFMA): per-point MLP layers 1-2.  Block = 512 points (4 m-tiles
// of 128).  h1 fragments built in-register, layer2 via f16 MFMA with W2
// B-fragments resident.  Epilogue: bias+relu+cvt through LDS, then store in
// fragment-major order — global chunk index == linear output index, fully
// coalesced sequential bursts.
// ---------------------------------------------------------------------------
__global__ __launch_bounds__(256, 2) void pointnet_l12(
    const float* __restrict__ x,
    const float* __restrict__ W1, const float* __restrict__ b1,
    const float* __restrict__ W2, const float* __restrict__ b2,
    f16* __restrict__ h2)
{
    __shared__ float xs[512*3];                    // 6 KB
    __shared__ float w1s[192], b1s[64], b2s[128];  // 1.5 KB
    __shared__ __align__(16) f16 h2s[128*136];     // 34.8 KB, +8 pad per row

    int tid = threadIdx.x;
    int P0 = blockIdx.x * 512;
    for (int i = tid; i < 1536; i += 256) xs[i] = x[(size_t)P0*3 + i];
    if (tid < 192) w1s[tid] = W1[tid];
    else b1s[tid - 192] = b1[tid - 192];
    if (tid < 128) b2s[tid] = b2[tid];

    int lane = tid & 63, wid = tid >> 6;
    int wr = wid & 1, wc = wid >> 1;
    int lrow = lane & 15, quad = lane >> 4;

    // B-fragments direct from fp32 W2 [64 k][128 n] (L2-resident, once/block)
    f16x8 bf[4][2];
#pragma unroll
    for (int ct = 0; ct < 4; ct++)
#pragma unroll
        for (int kc = 0; kc < 2; kc++) {
            int col = wc*64 + ct*16 + lrow;
#pragma unroll
            for (int j = 0; j < 8; j++)
                bf[ct][kc][j] = (f16)W2[(size_t)(kc*32 + quad*8 + j)*128 + col];
        }

    __syncthreads();

    for (int mt = 0; mt < 4; mt++) {
        f32x4 acc[4][4];
#pragma unroll
        for (int rt = 0; rt < 4; rt++)
#pragma unroll
            for (int ct = 0; ct < 4; ct++)
                acc[rt][ct] = (f32x4){0.f, 0.f, 0.f, 0.f};

#pragma unroll
        for (int kc = 0; kc < 2; kc++) {
            float wa[8], wb[8], wcv[8], bv[8];
#pragma unroll
            for (int j = 0; j < 8; j++) {
                int k = kc*32 + quad*8 + j;
                wa[j] = w1s[k]; wb[j] = w1s[64+k]; wcv[j] = w1s[128+k]; bv[j] = b1s[k];
            }
            f16x8 af[4];
#pragma unroll
            for (int rt = 0; rt < 4; rt++) {
                int p = mt*128 + wr*64 + rt*16 + lrow;
                float x0 = xs[p*3], x1 = xs[p*3+1], x2 = xs[p*3+2];
#pragma unroll
                for (int j = 0; j < 8; j++) {
                    float v = fmaf(x2, wcv[j], fmaf(x1, wb[j], fmaf(x0, wa[j], bv[j])));
                    af[rt][j] = (f16)fmaxf(v, 0.f);
                }
            }
#pragma unroll
            for (int rt = 0; rt < 4; rt++)
#pragma unroll
                for (int ct = 0; ct < 4; ct++)
                    acc[rt][ct] = __builtin_amdgcn_mfma_f32_16x16x32_f16(af[rt], bf[ct][kc], acc[rt][ct], 0, 0, 0);
        }

        __syncthreads();   // previous tile's h2s readers done
#pragma unroll
        for (int rt = 0; rt < 4; rt++)
#pragma unroll
            for (int ct = 0; ct < 4; ct++) {
                int col  = wc*64 + ct*16 + lrow;
                float bb = b2s[col];
                int rowb = wr*64 + rt*16 + quad*4;
#pragma unroll
                for (int r = 0; r < 4; r++) {
                    float v = fmaxf(acc[rt][ct][r] + bb, 0.f);
                    h2s[(rowb + r)*136 + col] = (f16)v;
                }
            }
        __syncthreads();
        // fragment-major store: output chunk index o is LINEAR -> coalesced.
        // decode o -> (g, kc, quad, lrow); source row = g*16+lrow, chunk c=kc*4+quad
        size_t gch = (((size_t)P0 + (size_t)mt*128) >> 4) * 256;  // chunk base
#pragma unroll
        for (int i = 0; i < 8; i++) {
            int o = i*256 + tid;               // 2048 chunks per 128-row tile
            int gg = o >> 8, rem = o & 255;
            int kc = rem >> 6, qd = (rem >> 4) & 3, lr = rem & 15;
            int row = gg*16 + lr, c = kc*4 + qd;
            f16x8 v = *(const f16x8*)(h2s + row*136 + c*8);
            *(f16x8*)(h2 + (gch + o)*8) = v;
        }
    }
}

// ---------------------------------------------------------------------------
// Kernel B: h2[1024x128] @ W3[128x1024] (f16 MFMA), bias+relu+max over points
// -> g[B][1024].  NO LDS, NO barriers.  B (W3) resident in VGPRs; A loaded
// global->VGPR as contiguous 1KB bursts (fragment-major h2).  Block =
// (b, 256-col strip); b=i&255 => same-b blocks share i%8 => same XCD => the
// 4x A re-read is L2-served.  launch_bounds(256,2): ~160 live VGPRs, NO
// spill (round-6 regression was the (256,3) cap forcing bf/acc to scratch).
// ---------------------------------------------------------------------------
__global__ __launch_bounds__(256, 2) void pointnet_l3_max(
    const f16* __restrict__ h2,    // [B][64 g][4 kc][4 quad][16 lrow] chunks
    const float* __restrict__ W3,  // [128][1024] fp32
    const float* __restrict__ b3,  // [1024]
    float* __restrict__ g)         // [B][1024]
{
    int i  = blockIdx.x;
    int b  = i & 255, nb = i >> 8;   // nb 0..3
    int tid = threadIdx.x;
    int lane = tid & 63, wid = tid >> 6;
    int lrow = lane & 15, quad = lane >> 4;
    int col0 = nb*256 + wid*64;

    // B-fragments direct from fp32 W3 [128 k][1024 n] (L2-resident)
    f16x8 bf[4][4];
#pragma unroll
    for (int ct = 0; ct < 4; ct++)
#pragma unroll
        for (int kc = 0; kc < 4; kc++) {
            int col = col0 + ct*16 + lrow;
#pragma unroll
            for (int j = 0; j < 8; j++)
                bf[ct][kc][j] = (f16)W3[(size_t)(kc*32 + quad*8 + j)*1024 + col];
        }

    float cmax[4] = {-3.0e38f, -3.0e38f, -3.0e38f, -3.0e38f};
    const f16* abase = h2 + (size_t)b * 131072 + lane*8;  // + lane chunk

    for (int m0 = 0; m0 < 1024; m0 += 128) {
        int gbase = m0 >> 4;   // group index base (8 groups per tile)
#pragma unroll
        for (int half = 0; half < 2; half++) {
            f32x4 acc[4][4];
#pragma unroll
            for (int rt = 0; rt < 4; rt++)
#pragma unroll
                for (int ct = 0; ct < 4; ct++)
                    acc[rt][ct] = (f32x4){0.f, 0.f, 0.f, 0.f};
#pragma unroll
            for (int kc = 0; kc < 4; kc++) {
                f16x8 af[4];
#pragma unroll
                for (int rt = 0; rt < 4; rt++)
                    af[rt] = *(const f16x8*)(abase + (size_t)(gbase + half*4 + rt)*2048 + kc*512);
#pragma unroll
                for (int rt = 0; rt < 4; rt++)
#pragma unroll
                    for (int ct = 0; ct < 4; ct++)
                        acc[rt][ct] = __builtin_amdgcn_mfma_f32_16x16x32_f16(af[rt], bf[ct][kc], acc[rt][ct], 0, 0, 0);
            }
            // fold rows into running col-max (bias+relu deferred: monotone)
#pragma unroll
            for (int rt = 0; rt < 4; rt++)
#pragma unroll
                for (int ct = 0; ct < 4; ct++)
#pragma unroll
                    for (int r = 0; r < 4; r += 2)
                        cmax[ct] = fmaxf(fmaxf(acc[rt][ct][r], acc[rt][ct][r+1]), cmax[ct]);
        }
    }

#pragma unroll
    for (int ct = 0; ct < 4; ct++) {
        cmax[ct] = fmaxf(cmax[ct], __shfl_xor(cmax[ct], 16, 64));
        cmax[ct] = fmaxf(cmax[ct], __shfl_xor(cmax[ct], 32, 64));
    }
    if (quad == 0) {
#pragma unroll
        for (int ct = 0; ct < 4; ct++) {
            int cg = col0 + ct*16 + lrow;
            g[(size_t)b*1024 + cg] = fmaxf(cmax[ct] + b3[cg], 0.f);
        }
    }
}

// ---------------------------------------------------------------------------
// Head layer 1 partials: zp1[kc][b][c] = sum_{k in chunk} g[b][k]*Wh1[k][c].
// Grid (cb=2, bb=64, kc=4) = 512 blocks; block 256 thr; 4 batches/block.
// ---------------------------------------------------------------------------
__global__ __launch_bounds__(256) void head_l1(
    const float* __restrict__ g, const float* __restrict__ Wh1,
    float* __restrict__ zp1)
{
    __shared__ float gs4[4][256];
    int cb = blockIdx.x, bb = blockIdx.y, kc = blockIdx.z;
    int tid = threadIdx.x;
    int b0 = bb * 4;
    int kbase = kc * 256;
#pragma unroll
    for (int j = 0; j < 4; j++) {
        int i = tid + j*256;
        gs4[i >> 8][i & 255] = g[(size_t)(b0 + (i >> 8))*1024 + kbase + (i & 255)];
    }
    __syncthreads();

    int c = cb*256 + tid;
    float acc[4] = {0.f, 0.f, 0.f, 0.f};
#pragma unroll 1
    for (int k = 0; k < 256; k += 8) {
        float w[8];
#pragma unroll
        for (int j = 0; j < 8; j++) w[j] = Wh1[(size_t)(kbase+k+j)*512 + c];
#pragma unroll
        for (int r = 0; r < 4; r++) {
            float4 a = *(const float4*)&gs4[r][k];
            float4 bq = *(const float4*)&gs4[r][k+4];
            acc[r] = fmaf(a.x, w[0], acc[r]);
            acc[r] = fmaf(a.y, w[1], acc[r]);
            acc[r] = fmaf(a.z, w[2], acc[r]);
            acc[r] = fmaf(a.w, w[3], acc[r]);
            acc[r] = fmaf(bq.x, w[4], acc[r]);
            acc[r] = fmaf(bq.y, w[5], acc[r]);
            acc[r] = fmaf(bq.z, w[6], acc[r]);
            acc[r] = fmaf(bq.w, w[7], acc[r]);
        }
    }
#pragma unroll
    for (int r = 0; r < 4; r++)
        zp1[((size_t)kc*256 + b0 + r)*512 + c] = acc[r];
}

// ---------------------------------------------------------------------------
// Head layer 2 partials, z1-reduce fused into staging.
// Grid (bb=128, kc2=4) = 512 blocks; block 256; 2 batches/block.
// ---------------------------------------------------------------------------
__global__ __launch_bounds__(256) void head_l2(
    const float* __restrict__ zp1, const float* __restrict__ bh1,
    const float* __restrict__ Wh2, float* __restrict__ zp2)
{
    __shared__ float z1s[2][128];
    int bb = blockIdx.x, kc2 = blockIdx.y;
    int tid = threadIdx.x;
    int b0 = bb * 2;
    int kb = kc2 * 128;
    {
        int row = tid >> 7, kk = tid & 127;
        int col = kb + kk;
        float v = bh1[col];
#pragma unroll
        for (int j = 0; j < 4; j++)
            v += zp1[((size_t)j*256 + b0 + row)*512 + col];
        z1s[row][kk] = fmaxf(v, 0.f);
    }
    __syncthreads();

    int c = tid;
    float acc0 = 0.f, acc1 = 0.f;
#pragma unroll 1
    for (int k = 0; k < 128; k += 8) {
        float w[8];
#pragma unroll
        for (int j = 0; j < 8; j++) w[j] = Wh2[(size_t)(kb+k+j)*256 + c];
        float4 a0 = *(const float4*)&z1s[0][k];
        float4 a1 = *(const float4*)&z1s[0][k+4];
        float4 d0 = *(const float4*)&z1s[1][k];
        float4 d1 = *(const float4*)&z1s[1][k+4];
        acc0 = fmaf(a0.x, w[0], acc0);  acc1 = fmaf(d0.x, w[0], acc1);
        acc0 = fmaf(a0.y, w[1], acc0);  acc1 = fmaf(d0.y, w[1], acc1);
        acc0 = fmaf(a0.z, w[2], acc0);  acc1 = fmaf(d0.z, w[2], acc1);
        acc0 = fmaf(a0.w, w[3], acc0);  acc1 = fmaf(d0.w, w[3], acc1);
        acc0 = fmaf(a1.x, w[4], acc0);  acc1 = fmaf(d1.x, w[4], acc1);
        acc0 = fmaf(a1.y, w[5], acc0);  acc1 = fmaf(d1.y, w[5], acc1);
        acc0 = fmaf(a1.z, w[6], acc0);  acc1 = fmaf(d1.z, w[6], acc1);
        acc0 = fmaf(a1.w, w[7], acc0);  acc1 = fmaf(d1.w, w[7], acc1);
    }
    zp2[((size_t)kc2*256 + b0    )*256 + c] = acc0;
    zp2[((size_t)kc2*256 + b0 + 1)*256 + c] = acc1;
}

// ---------------------------------------------------------------------------
// SVD -> SO(3) projection, fp64 Jacobi on M^T M (per-thread serial)
// ---------------------------------------------------------------------------
__device__ inline void jrot(double S[3][3], double V[3][3], int p, int q)
{
    double apq = S[p][q];
    if (fabs(apq) < 1e-36) return;
    double tau = (S[q][q] - S[p][p]) / (2.0 * apq);
    double t = (tau >= 0.0 ? 1.0 : -1.0) / (fabs(tau) + sqrt(1.0 + tau*tau));
    double c = 1.0 / sqrt(1.0 + t*t);
    double s = t * c;
    for (int k = 0; k < 3; k++) {
        double skp = S[k][p], skq = S[k][q];
        S[k][p] = c*skp - s*skq;  S[k][q] = s*skp + c*skq;
    }
    for (int k = 0; k < 3; k++) {
        double spk = S[p][k], sqk = S[q][k];
        S[p][k] = c*spk - s*sqk;  S[q][k] = s*spk + c*sqk;
    }
    for (int k = 0; k < 3; k++) {
        double vkp = V[k][p], vkq = V[k][q];
        V[k][p] = c*vkp - s*vkq;  V[k][q] = s*vkp + c*vkq;
    }
}

__device__ void svd_so3(const float* Mf, float* Rout)
{
    double M[3][3], S[3][3], V[3][3];
    for (int i = 0; i < 3; i++)
        for (int j = 0; j < 3; j++) M[i][j] = (double)Mf[3*i+j];
    for (int i = 0; i < 3; i++)
        for (int j = 0; j < 3; j++)
            S[i][j] = M[0][i]*M[0][j] + M[1][i]*M[1][j] + M[2][i]*M[2][j];
    for (int i = 0; i < 3; i++)
        for (int j = 0; j < 3; j++) V[i][j] = (i == j) ? 1.0 : 0.0;
    for (int it = 0; it < 10; it++) {
        jrot(S, V, 0, 1); jrot(S, V, 0, 2); jrot(S, V, 1, 2);
    }
    double lam[3] = {S[0][0], S[1][1], S[2][2]};
    int i0 = 0, i1 = 1, i2 = 2, tt;
    if (lam[i0] < lam[i1]) { tt = i0; i0 = i1; i1 = tt; }
    if (lam[i0] < lam[i2]) { tt = i0; i0 = i2; i2 = tt; }
    if (lam[i1] < lam[i2]) { tt = i1; i1 = i2; i2 = tt; }
    double v0[3], v1[3], v2[3];
    for (int k = 0; k < 3; k++) { v0[k] = V[k][i0]; v1[k] = V[k][i1]; v2[k] = V[k][i2]; }
    double u1[3], u2[3], u3[3];
    for (int i = 0; i < 3; i++) u1[i] = M[i][0]*v0[0] + M[i][1]*v0[1] + M[i][2]*v0[2];
    double n1 = sqrt(u1[0]*u1[0] + u1[1]*u1[1] + u1[2]*u1[2]) + 1e-300;
    for (int i = 0; i < 3; i++) u1[i] /= n1;
    for (int i = 0; i < 3; i++) u2[i] = M[i][0]*v1[0] + M[i][1]*v1[1] + M[i][2]*v1[2];
    double d12 = u1[0]*u2[0] + u1[1]*u2[1] + u1[2]*u2[2];
    for (int i = 0; i < 3; i++) u2[i] -= d12*u1[i];
    double n2 = sqrt(u2[0]*u2[0] + u2[1]*u2[1] + u2[2]*u2[2]) + 1e-300;
    for (int i = 0; i < 3; i++) u2[i] /= n2;
    u3[0] = u1[1]*u2[2] - u1[2]*u2[1];
    u3[1] = u1[2]*u2[0] - u1[0]*u2[2];
    u3[2] = u1[0]*u2[1] - u1[1]*u2[0];
    double c12x = v1[1]*v2[2] - v1[2]*v2[1];
    double c12y = v1[2]*v2[0] - v1[0]*v2[2];
    double c12z = v1[0]*v2[1] - v1[1]*v2[0];
    double detV = v0[0]*c12x + v0[1]*c12y + v0[2]*c12z;
    for (int i = 0; i < 3; i++)
        for (int j = 0; j < 3; j++)
            Rout[3*i+j] = (float)(u1[i]*v0[j] + u2[i]*v1[j] + detV*u3[i]*v2[j]);
}

// ---------------------------------------------------------------------------
// Head tail: z2-reduce + (z2 @ Wh3 + bh3) + SVD. Wh3 staged in LDS.
// 8 batches/block, 32 blocks x 128 threads.
// ---------------------------------------------------------------------------
__global__ __launch_bounds__(128) void head_l3_svd(
    const float* __restrict__ zp2, const float* __restrict__ bh2,
    const float* __restrict__ Wh3, const float* __restrict__ bh3,
    float* __restrict__ out)
{
    __shared__ float z2s[8][256];
    __shared__ float wh3s[2304];
    __shared__ float raws[8][12];
    int b0 = blockIdx.x * 8;
    int tid = threadIdx.x;

    for (int i = tid; i < 2304; i += 128) wh3s[i] = Wh3[i];
    for (int i = tid; i < 8*256; i += 128) {
        int row = i >> 8, kk = i & 255;
        float v = bh2[kk];
#pragma unroll
        for (int j = 0; j < 4; j++)
            v += zp2[((size_t)j*256 + b0 + row)*256 + kk];
        z2s[row][kk] = fmaxf(v, 0.f);
    }
    __syncthreads();

    if (tid < 72) {
        int r = tid / 9, c = tid % 9;
        float acc = bh3[c];
#pragma unroll 8
        for (int k = 0; k < 256; k++) acc = fmaf(z2s[r][k], wh3s[k*9 + c], acc);
        raws[r][c] = acc;
    }
    __syncthreads();

    if (tid < 8) svd_so3(&raws[tid][0], out + (size_t)(b0 + tid)*9);
}

// ---------------------------------------------------------------------------
extern "C" void kernel_launch(void* const* d_in, const int* in_sizes, int n_in,
                              void* d_out, int out_size, void* d_ws, size_t ws_size,
                              hipStream_t stream)
{
    const float* x   = (const float*)d_in[0];
    const float* W1  = (const float*)d_in[1];
    const float* b1  = (const float*)d_in[2];
    const float* W2  = (const float*)d_in[3];
    const float* b2  = (const float*)d_in[4];
    const float* W3  = (const float*)d_in[5];
    const float* b3  = (const float*)d_in[6];
    const float* Wh1 = (const float*)d_in[7];
    const float* bh1 = (const float*)d_in[8];
    const float* Wh2 = (const float*)d_in[9];
    const float* bh2 = (const float*)d_in[10];
    const float* Wh3 = (const float*)d_in[11];
    const float* bh3 = (const float*)d_in[12];
    float* out = (float*)d_out;

    char* ws = (char*)d_ws;
    f16*   h2  = (f16*)ws;                                  // 64 MB
    float* g   = (float*)(ws + (size_t)67108864);           // 1 MB
    float* zp1 = (float*)(ws + (size_t)67108864 + 1048576);            // 2 MB
    float* zp2 = (float*)(ws + (size_t)67108864 + 1048576 + 2097152);  // 1 MB

    pointnet_l12<<<512, 256, 0, stream>>>(x, W1, b1, W2, b2, h2);
    pointnet_l3_max<<<1024, 256, 0, stream>>>(h2, W3, b3, g);
    dim3 gridH1(2, 64, 4);
    head_l1<<<gridH1, 256, 0, stream>>>(g, Wh1, zp1);
    dim3 gridH2(128, 4);
    head_l2<<<gridH2, 256, 0, stream>>>(zp1, bh1, Wh2, zp2);
    head_l3_svd<<<32, 128, 0, stream>>>(zp2, bh2, Wh3, bh3, out);
}